// Round 14
// baseline (489.025 us; speedup 1.0000x reference)
//
#include <hip/hip_runtime.h>
#include <hip/hip_fp16.h>

#define FDIM 128
#define NCLS 16

#define SCAN_T 256
#define SCAN_I 8
#define SCAN_CHUNK (SCAN_T * SCAN_I)  // 2048 elements per block

typedef _Float16 f16x8 __attribute__((ext_vector_type(8)));
typedef float f32x4 __attribute__((ext_vector_type(4)));

// ---------------- CSR build ----------------
__global__ void k_count(const int* __restrict__ dst, int* cnt, int e) {
    int i = blockIdx.x * blockDim.x + threadIdx.x;
    if (i < e) atomicAdd(&cnt[dst[i]], 1);
}

// phase 1: block-local exclusive scan, per-block total; also computes dinv
__global__ __launch_bounds__(SCAN_T) void k_scan1(const int* __restrict__ cnt,
                                                  int* __restrict__ excl,
                                                  int* __restrict__ blockSum,
                                                  float* __restrict__ dinv, int n) {
    __shared__ int ts[SCAN_T];
    int b = blockIdx.x, t = threadIdx.x;
    int base = b * SCAN_CHUNK + t * SCAN_I;
    int v[SCAN_I];
    int s = 0;
    #pragma unroll
    for (int i = 0; i < SCAN_I; ++i) {
        int idx = base + i;
        v[i] = (idx < n) ? cnt[idx] : 0;
        if (idx < n) dinv[idx] = rsqrtf((float)(v[i] + 1));  // +1 self-loop
        s += v[i];
    }
    ts[t] = s;
    __syncthreads();
    for (int off = 1; off < SCAN_T; off <<= 1) {
        int x = (t >= off) ? ts[t - off] : 0;
        __syncthreads();
        ts[t] += x;
        __syncthreads();
    }
    int ex = (t == 0) ? 0 : ts[t - 1];
    #pragma unroll
    for (int i = 0; i < SCAN_I; ++i) {
        int idx = base + i;
        if (idx < n) excl[idx] = ex;
        ex += v[i];
    }
    if (t == SCAN_T - 1) blockSum[b] = ts[SCAN_T - 1];
}

// phase 2 (block 0) + W pre-transpose (blocks 1,2) in one launch
__global__ __launch_bounds__(1024) void k_scan2_prepw(int* blockSum, int* total, int nb,
                                                      const float* __restrict__ W1,
                                                      const float* __restrict__ W2,
                                                      __half* __restrict__ T1,
                                                      __half* __restrict__ T2) {
    if (blockIdx.x == 0) {
        __shared__ int ts[1024];
        int t = threadIdx.x;
        int v = (t < nb) ? blockSum[t] : 0;
        ts[t] = v;
        __syncthreads();
        for (int off = 1; off < 1024; off <<= 1) {
            int x = (t >= off) ? ts[t - off] : 0;
            __syncthreads();
            ts[t] += x;
            __syncthreads();
        }
        if (t < nb) blockSum[t] = (t == 0) ? 0 : ts[t - 1];
        if (t == 1023) *total = ts[1023];
    } else {
        const float* W = (blockIdx.x == 1) ? W1 : W2;
        __half* T = (blockIdx.x == 1) ? T1 : T2;
        for (int i = threadIdx.x; i < 128 * 32; i += 1024) {
            int c = i >> 5, k4 = (i & 31) * 4;  // output [c][k4..k4+3]
            float a = W[(k4 + 0) * 128 + c];
            float b = W[(k4 + 1) * 128 + c];
            float d = W[(k4 + 2) * 128 + c];
            float f = W[(k4 + 3) * 128 + c];
            __half2 h0 = __float22half2_rn(make_float2(a, b));
            __half2 h1 = __float22half2_rn(make_float2(d, f));
            uint2 u;
            u.x = *reinterpret_cast<unsigned int*>(&h0);
            u.y = *reinterpret_cast<unsigned int*>(&h1);
            *reinterpret_cast<uint2*>(&T[c * 128 + k4]) = u;
        }
    }
}

// phase 3: add block offsets, copy to cursor, write row_ptr[n]
__global__ void k_scan3(int* __restrict__ row_ptr, int* __restrict__ cursor,
                        const int* __restrict__ blockSum, const int* __restrict__ total,
                        int n) {
    int i = blockIdx.x * blockDim.x + threadIdx.x;
    if (i < n) {
        int v = row_ptr[i] + blockSum[i / SCAN_CHUNK];
        row_ptr[i] = v;
        cursor[i] = v;
    }
    if (i == 0) row_ptr[n] = *total;
}

// scatter: store BYTE offset of the fp16 source row (src * 256)
__global__ void k_scatter(const int* __restrict__ src, const int* __restrict__ dst,
                          int* cursor, int* __restrict__ csr_off, int e) {
    int i = blockIdx.x * blockDim.x + threadIdx.x;
    if (i >= e) return;
    int pos = atomicAdd(&cursor[dst[i]], 1);
    csr_off[pos] = src[i] << 8;  // fp16 row stride = 128*2 = 256 B
}

// ------- MFMA GEMM: Y[n,128](fp16) = (A[n,128] @ W[128,128]) * dinv[row] -------
template <typename T>
__global__ __launch_bounds__(512) void k_gemm_mfma(const T* __restrict__ A,
                                                   const __half* __restrict__ WT,
                                                   const float* __restrict__ dinv,
                                                   __half* __restrict__ C, int n) {
    __shared__ _Float16 as[128 * 128];   // 32 KB  [r][k] swizzled
    __shared__ _Float16 wt[128 * 128];   // 32 KB  [c][k] swizzled
    int t = threadIdx.x;
    int r0 = blockIdx.x * 128;

    for (int i = t; i < 2048; i += 512) {
        int c = i >> 4, k8 = i & 15;
        uint4 u = reinterpret_cast<const uint4*>(WT)[i];
        int byte = (c * 256 + k8 * 16) ^ ((c & 7) << 4);
        *reinterpret_cast<uint4*>(reinterpret_cast<char*>(wt) + byte) = u;
    }

    if constexpr (sizeof(T) == 4) {
        for (int i = t; i < 128 * 16; i += 512) {
            int r = i >> 4, c8 = i & 15;
            float4 v0 = make_float4(0.f, 0.f, 0.f, 0.f);
            float4 v1 = make_float4(0.f, 0.f, 0.f, 0.f);
            if (r0 + r < n) {
                v0 = reinterpret_cast<const float4*>(A)[(size_t)(r0 + r) * 32 + c8 * 2];
                v1 = reinterpret_cast<const float4*>(A)[(size_t)(r0 + r) * 32 + c8 * 2 + 1];
            }
            __half2 h0 = __float22half2_rn(make_float2(v0.x, v0.y));
            __half2 h1 = __float22half2_rn(make_float2(v0.z, v0.w));
            __half2 h2 = __float22half2_rn(make_float2(v1.x, v1.y));
            __half2 h3 = __float22half2_rn(make_float2(v1.z, v1.w));
            uint4 u;
            u.x = *reinterpret_cast<unsigned int*>(&h0);
            u.y = *reinterpret_cast<unsigned int*>(&h1);
            u.z = *reinterpret_cast<unsigned int*>(&h2);
            u.w = *reinterpret_cast<unsigned int*>(&h3);
            int byte = (r * 256 + c8 * 16) ^ ((r & 7) << 4);
            *reinterpret_cast<uint4*>(reinterpret_cast<char*>(as) + byte) = u;
        }
    } else {
        for (int i = t; i < 128 * 16; i += 512) {
            int r = i >> 4, c8 = i & 15;
            uint4 u = make_uint4(0, 0, 0, 0);
            if (r0 + r < n)
                u = reinterpret_cast<const uint4*>(A)[(size_t)(r0 + r) * 16 + c8];
            int byte = (r * 256 + c8 * 16) ^ ((r & 7) << 4);
            *reinterpret_cast<uint4*>(reinterpret_cast<char*>(as) + byte) = u;
        }
    }
    __syncthreads();

    int w = t >> 6, l = t & 63;
    int lrow = l & 15, lk = l >> 4;
    int rw = w * 16;

    f16x8 afrag[4];
    #pragma unroll
    for (int ks = 0; ks < 4; ++ks) {
        int row = rw + lrow;
        int byte = (row * 256 + (ks * 4 + lk) * 16) ^ ((row & 7) << 4);
        afrag[ks] = *reinterpret_cast<const f16x8*>(reinterpret_cast<const char*>(as) + byte);
    }
    float dv[4];
    #pragma unroll
    for (int reg = 0; reg < 4; ++reg) {
        int rg = r0 + rw + lk * 4 + reg;
        dv[reg] = (rg < n) ? dinv[rg] : 0.f;
    }

    #pragma unroll
    for (int ct = 0; ct < 8; ++ct) {
        f32x4 acc = {0.f, 0.f, 0.f, 0.f};
        #pragma unroll
        for (int ks = 0; ks < 4; ++ks) {
            int c = ct * 16 + lrow;
            int byte = (c * 256 + (ks * 4 + lk) * 16) ^ ((c & 7) << 4);
            f16x8 bfrag = *reinterpret_cast<const f16x8*>(reinterpret_cast<const char*>(wt) + byte);
            acc = __builtin_amdgcn_mfma_f32_16x16x32_f16(afrag[ks], bfrag, acc, 0, 0, 0);
        }
        #pragma unroll
        for (int reg = 0; reg < 4; ++reg) {
            int rg = r0 + rw + lk * 4 + reg;
            if (rg < n)
                C[(size_t)rg * FDIM + ct * 16 + lrow] = __float2half(acc[reg] * dv[reg]);
        }
    }
}

// -------- aggregation V4 (both layers): 4 edges per dwordx4 load --------
// 16 lanes per edge (grp = lane>>4); lane serves bytes (lane&15)*16 of the row.
// Offsets via one __shfl (bpermute) per 4 edges. Depth-1 hadd2 fold, f32 accum.
// Cross-group combine at end (shfl_xor 16,32); self added post-combine.
template <bool FUSE>
__global__ __launch_bounds__(256) void k_agg4e(const __half* __restrict__ Y,
                                               const int* __restrict__ csr_off,
                                               const int* __restrict__ row_ptr,
                                               const float* __restrict__ dinv,
                                               const float* __restrict__ bias,
                                               const float* __restrict__ Wl,
                                               const float* __restrict__ bl,
                                               __half* __restrict__ hout,
                                               float* __restrict__ out, int n) {
    __shared__ float s_wl[NCLS * FDIM];  // transposed: [c][k]
    __shared__ float s_bl[NCLS];
    if (FUSE) {
        for (int i = threadIdx.x; i < FDIM * NCLS / 4; i += 256) {
            int k = i >> 2, c4 = (i & 3) * 4;
            float4 v = reinterpret_cast<const float4*>(Wl)[i];
            s_wl[(c4 + 0) * FDIM + k] = v.x;
            s_wl[(c4 + 1) * FDIM + k] = v.y;
            s_wl[(c4 + 2) * FDIM + k] = v.z;
            s_wl[(c4 + 3) * FDIM + k] = v.w;
        }
        if (threadIdx.x < NCLS) s_bl[threadIdx.x] = bl[threadIdx.x];
        __syncthreads();
    }

    int node = blockIdx.x * 4 + (threadIdx.x >> 6);
    if (node >= n) return;
    int lane = threadIdx.x & 63;
    int grp = lane >> 4, l16 = lane & 15;
    const char* Yb = reinterpret_cast<const char*>(Y);
    const char* lanebase = Yb + l16 * 16;  // loop-invariant 16B slice

    // f32 accumulators for this lane's 8 dims (elements l16*8 .. +7)
    float2 A0 = {0.f, 0.f}, A1 = {0.f, 0.f}, A2 = {0.f, 0.f}, A3 = {0.f, 0.f};
    int beg = row_ptr[node], end = row_ptr[node + 1];

    for (int j0 = beg; j0 < end; j0 += 64) {
        int cnt = min(64, end - j0);
        int myoff = (j0 + lane < end) ? csr_off[j0 + lane] : 0;
        int k = 0;
        for (; k + 8 <= cnt; k += 8) {
            int o1 = __shfl(myoff, k + grp, 64);
            int o2 = __shfl(myoff, k + 4 + grp, 64);
            uint4 u1 = *reinterpret_cast<const uint4*>(lanebase + o1);
            uint4 u2 = *reinterpret_cast<const uint4*>(lanebase + o2);
            __half2* p1 = reinterpret_cast<__half2*>(&u1);
            __half2* p2 = reinterpret_cast<__half2*>(&u2);
            __half2 s0 = __hadd2(p1[0], p2[0]);
            __half2 s1 = __hadd2(p1[1], p2[1]);
            __half2 s2 = __hadd2(p1[2], p2[2]);
            __half2 s3 = __hadd2(p1[3], p2[3]);
            float2 f0 = __half22float2(s0), f1 = __half22float2(s1);
            float2 f2 = __half22float2(s2), f3 = __half22float2(s3);
            A0.x += f0.x; A0.y += f0.y; A1.x += f1.x; A1.y += f1.y;
            A2.x += f2.x; A2.y += f2.y; A3.x += f3.x; A3.y += f3.y;
        }
        for (; k + 4 <= cnt; k += 4) {
            int o = __shfl(myoff, k + grp, 64);
            uint4 u = *reinterpret_cast<const uint4*>(lanebase + o);
            __half2* p = reinterpret_cast<__half2*>(&u);
            float2 f0 = __half22float2(p[0]), f1 = __half22float2(p[1]);
            float2 f2 = __half22float2(p[2]), f3 = __half22float2(p[3]);
            A0.x += f0.x; A0.y += f0.y; A1.x += f1.x; A1.y += f1.y;
            A2.x += f2.x; A2.y += f2.y; A3.x += f3.x; A3.y += f3.y;
        }
        if (k < cnt) {  // 1-3 edges remain: groups >= rem replicate & mask
            int rem = cnt - k;
            int o = __shfl(myoff, k + min(grp, rem - 1), 64);
            uint4 u = *reinterpret_cast<const uint4*>(lanebase + o);
            __half2* p = reinterpret_cast<__half2*>(&u);
            float sel = (grp < rem) ? 1.0f : 0.0f;
            float2 f0 = __half22float2(p[0]), f1 = __half22float2(p[1]);
            float2 f2 = __half22float2(p[2]), f3 = __half22float2(p[3]);
            A0.x += f0.x * sel; A0.y += f0.y * sel;
            A1.x += f1.x * sel; A1.y += f1.y * sel;
            A2.x += f2.x * sel; A2.y += f2.y * sel;
            A3.x += f3.x * sel; A3.y += f3.y * sel;
        }
    }

    // cross-group combine: lanes {l, l^16, l^32, l^48} hold same dims
    #pragma unroll
    for (int off = 16; off <= 32; off <<= 1) {
        A0.x += __shfl_xor(A0.x, off, 64); A0.y += __shfl_xor(A0.y, off, 64);
        A1.x += __shfl_xor(A1.x, off, 64); A1.y += __shfl_xor(A1.y, off, 64);
        A2.x += __shfl_xor(A2.x, off, 64); A2.y += __shfl_xor(A2.y, off, 64);
        A3.x += __shfl_xor(A3.x, off, 64); A3.y += __shfl_xor(A3.y, off, 64);
    }

    // self term (all lanes hold the full edge-sum now; add once per copy)
    {
        uint4 u = *reinterpret_cast<const uint4*>(Yb + ((size_t)node << 8) + l16 * 16);
        __half2* p = reinterpret_cast<__half2*>(&u);
        float2 f0 = __half22float2(p[0]), f1 = __half22float2(p[1]);
        float2 f2 = __half22float2(p[2]), f3 = __half22float2(p[3]);
        A0.x += f0.x; A0.y += f0.y; A1.x += f1.x; A1.y += f1.y;
        A2.x += f2.x; A2.y += f2.y; A3.x += f3.x; A3.y += f3.y;
    }

    float di = dinv[node];
    float4 ba = *reinterpret_cast<const float4*>(bias + l16 * 8);
    float4 bb = *reinterpret_cast<const float4*>(bias + l16 * 8 + 4);
    float h0 = fmaxf(A0.x * di + ba.x, 0.f);
    float h1 = fmaxf(A0.y * di + ba.y, 0.f);
    float h2 = fmaxf(A1.x * di + ba.z, 0.f);
    float h3 = fmaxf(A1.y * di + ba.w, 0.f);
    float h4 = fmaxf(A2.x * di + bb.x, 0.f);
    float h5 = fmaxf(A2.y * di + bb.y, 0.f);
    float h6 = fmaxf(A3.x * di + bb.z, 0.f);
    float h7 = fmaxf(A3.y * di + bb.w, 0.f);

    if (!FUSE) {
        if (grp == 0) {
            __half2 o0 = __float22half2_rn(make_float2(h0, h1));
            __half2 o1 = __float22half2_rn(make_float2(h2, h3));
            __half2 o2 = __float22half2_rn(make_float2(h4, h5));
            __half2 o3 = __float22half2_rn(make_float2(h6, h7));
            uint4 o;
            o.x = *reinterpret_cast<unsigned int*>(&o0);
            o.y = *reinterpret_cast<unsigned int*>(&o1);
            o.z = *reinterpret_cast<unsigned int*>(&o2);
            o.w = *reinterpret_cast<unsigned int*>(&o3);
            *reinterpret_cast<uint4*>(reinterpret_cast<char*>(hout) + ((size_t)node << 8) + l16 * 16) = o;
        }
    } else {
        // per-lane partial logits over this lane's 8 dims (cols l16*8..+7)
        float lg[NCLS];
        #pragma unroll
        for (int c = 0; c < NCLS; ++c) {
            float4 wa = *reinterpret_cast<const float4*>(&s_wl[c * FDIM + l16 * 8]);
            float4 wb = *reinterpret_cast<const float4*>(&s_wl[c * FDIM + l16 * 8 + 4]);
            lg[c] = h0 * wa.x + h1 * wa.y + h2 * wa.z + h3 * wa.w +
                    h4 * wb.x + h5 * wb.y + h6 * wb.z + h7 * wb.w;
        }
        // butterfly within each 16-lane group (all groups end identical)
        #pragma unroll
        for (int off = 1; off < 16; off <<= 1) {
            #pragma unroll
            for (int c = 0; c < NCLS; ++c) lg[c] += __shfl_xor(lg[c], off, 64);
        }
        #pragma unroll
        for (int c = 0; c < NCLS; ++c) lg[c] += s_bl[c];
        float m = lg[0];
        #pragma unroll
        for (int c = 1; c < NCLS; ++c) m = fmaxf(m, lg[c]);
        float ev[NCLS];
        float sum = 0.f;
        #pragma unroll
        for (int c = 0; c < NCLS; ++c) { ev[c] = __expf(lg[c] - m); sum += ev[c]; }
        float inv = 1.0f / sum;
        float mye = 0.f;
        #pragma unroll
        for (int c = 0; c < NCLS; ++c) if (lane == c) mye = ev[c];  // static idx
        if (lane < NCLS) out[(size_t)node * NCLS + lane] = mye * inv;
    }
}

extern "C" void kernel_launch(void* const* d_in, const int* in_sizes, int n_in,
                              void* d_out, int out_size, void* d_ws, size_t ws_size,
                              hipStream_t stream) {
    const float* x  = (const float*)d_in[0];
    const int*   ei = (const int*)d_in[1];
    const float* W1 = (const float*)d_in[2];
    const float* b1 = (const float*)d_in[3];
    const float* W2 = (const float*)d_in[4];
    const float* b2 = (const float*)d_in[5];
    const float* Wl = (const float*)d_in[6];
    const float* bl = (const float*)d_in[7];
    float* out = (float*)d_out;

    int n = in_sizes[0] / FDIM;
    int e = in_sizes[1] / 2;
    const int* src = ei;
    const int* dst = ei + e;

    int nb = (n + SCAN_CHUNK - 1) / SCAN_CHUNK;  // <=1024

    // workspace layout (R11/R13-proven)
    float* dinv    = (float*)d_ws;                     // n
    int*   cnt     = (int*)(dinv + n);                 // n
    int*   row_ptr = cnt + n;                          // n+1
    int*   cursor  = row_ptr + n + 1;                  // n
    int*   blockSum= cursor + n;                       // nb (<=1024)
    int*   total   = blockSum + 1024;                  // 1
    int*   csr_off = total + 1;                        // e
    uintptr_t p = (uintptr_t)(csr_off + e);
    p = (p + 15) & ~(uintptr_t)15;
    __half* wt1 = (__half*)p;                          // 128*128
    __half* wt2 = wt1 + 128 * 128;                     // 128*128
    __half* bufA = wt2 + 128 * 128;                    // n*128 halves
    __half* bufB = bufA + (size_t)n * FDIM;            // n*128 halves

    int bn = (n + 255) / 256;
    int be = (e + 255) / 256;

    // CSR + norms + weight prep
    hipMemsetAsync(cnt, 0, (size_t)n * sizeof(int), stream);
    k_count<<<be, 256, 0, stream>>>(dst, cnt, e);
    k_scan1<<<nb, SCAN_T, 0, stream>>>(cnt, row_ptr, blockSum, dinv, n);
    k_scan2_prepw<<<3, 1024, 0, stream>>>(blockSum, total, nb, W1, W2, wt1, wt2);
    k_scan3<<<bn, 256, 0, stream>>>(row_ptr, cursor, blockSum, total, n);
    k_scatter<<<be, 256, 0, stream>>>(src, dst, cursor, csr_off, e);

    int bg = (n + 127) / 128;
    int ba = (n + 3) / 4;

    // layer 1
    k_gemm_mfma<float><<<bg, 512, 0, stream>>>(x, wt1, dinv, bufA, n);
    k_agg4e<false><<<ba, 256, 0, stream>>>(bufA, csr_off, row_ptr, dinv, b1, Wl, bl, bufB, out, n);

    // layer 2 (+ fused classifier/softmax)
    k_gemm_mfma<__half><<<bg, 512, 0, stream>>>(bufB, wt2, dinv, bufA, n);
    k_agg4e<true><<<ba, 256, 0, stream>>>(bufA, csr_off, row_ptr, dinv, b2, Wl, bl, bufB, out, n);
}

// Round 15
// 461.503 us; speedup vs baseline: 1.0596x; 1.0596x over previous
//
#include <hip/hip_runtime.h>
#include <hip/hip_fp16.h>

#define FDIM 128
#define NCLS 16

#define SCAN_T 256
#define SCAN_I 8
#define SCAN_CHUNK (SCAN_T * SCAN_I)  // 2048 elements per block

typedef _Float16 f16x8 __attribute__((ext_vector_type(8)));
typedef float f32x4 __attribute__((ext_vector_type(4)));

// ---------------- CSR build ----------------
__global__ void k_count(const int* __restrict__ dst, int* cnt, int e) {
    int i = blockIdx.x * blockDim.x + threadIdx.x;
    if (i < e) atomicAdd(&cnt[dst[i]], 1);
}

// phase 1: block-local exclusive scan, per-block total; also computes dinv
__global__ __launch_bounds__(SCAN_T) void k_scan1(const int* __restrict__ cnt,
                                                  int* __restrict__ excl,
                                                  int* __restrict__ blockSum,
                                                  float* __restrict__ dinv, int n) {
    __shared__ int ts[SCAN_T];
    int b = blockIdx.x, t = threadIdx.x;
    int base = b * SCAN_CHUNK + t * SCAN_I;
    int v[SCAN_I];
    int s = 0;
    #pragma unroll
    for (int i = 0; i < SCAN_I; ++i) {
        int idx = base + i;
        v[i] = (idx < n) ? cnt[idx] : 0;
        if (idx < n) dinv[idx] = rsqrtf((float)(v[i] + 1));  // +1 self-loop
        s += v[i];
    }
    ts[t] = s;
    __syncthreads();
    for (int off = 1; off < SCAN_T; off <<= 1) {
        int x = (t >= off) ? ts[t - off] : 0;
        __syncthreads();
        ts[t] += x;
        __syncthreads();
    }
    int ex = (t == 0) ? 0 : ts[t - 1];
    #pragma unroll
    for (int i = 0; i < SCAN_I; ++i) {
        int idx = base + i;
        if (idx < n) excl[idx] = ex;
        ex += v[i];
    }
    if (t == SCAN_T - 1) blockSum[b] = ts[SCAN_T - 1];
}

// phase 2 (block 0) + W pre-transpose (blocks 1,2) in one launch
__global__ __launch_bounds__(1024) void k_scan2_prepw(int* blockSum, int* total, int nb,
                                                      const float* __restrict__ W1,
                                                      const float* __restrict__ W2,
                                                      __half* __restrict__ T1,
                                                      __half* __restrict__ T2) {
    if (blockIdx.x == 0) {
        __shared__ int ts[1024];
        int t = threadIdx.x;
        int v = (t < nb) ? blockSum[t] : 0;
        ts[t] = v;
        __syncthreads();
        for (int off = 1; off < 1024; off <<= 1) {
            int x = (t >= off) ? ts[t - off] : 0;
            __syncthreads();
            ts[t] += x;
            __syncthreads();
        }
        if (t < nb) blockSum[t] = (t == 0) ? 0 : ts[t - 1];
        if (t == 1023) *total = ts[1023];
    } else {
        const float* W = (blockIdx.x == 1) ? W1 : W2;
        __half* T = (blockIdx.x == 1) ? T1 : T2;
        for (int i = threadIdx.x; i < 128 * 32; i += 1024) {
            int c = i >> 5, k4 = (i & 31) * 4;  // output [c][k4..k4+3]
            float a = W[(k4 + 0) * 128 + c];
            float b = W[(k4 + 1) * 128 + c];
            float d = W[(k4 + 2) * 128 + c];
            float f = W[(k4 + 3) * 128 + c];
            __half2 h0 = __float22half2_rn(make_float2(a, b));
            __half2 h1 = __float22half2_rn(make_float2(d, f));
            uint2 u;
            u.x = *reinterpret_cast<unsigned int*>(&h0);
            u.y = *reinterpret_cast<unsigned int*>(&h1);
            *reinterpret_cast<uint2*>(&T[c * 128 + k4]) = u;
        }
    }
}

// phase 3: add block offsets, copy to cursor, write row_ptr[n]
__global__ void k_scan3(int* __restrict__ row_ptr, int* __restrict__ cursor,
                        const int* __restrict__ blockSum, const int* __restrict__ total,
                        int n) {
    int i = blockIdx.x * blockDim.x + threadIdx.x;
    if (i < n) {
        int v = row_ptr[i] + blockSum[i / SCAN_CHUNK];
        row_ptr[i] = v;
        cursor[i] = v;
    }
    if (i == 0) row_ptr[n] = *total;
}

// scatter: store BYTE offset of the fp16 source row (src * 256)
__global__ void k_scatter(const int* __restrict__ src, const int* __restrict__ dst,
                          int* cursor, int* __restrict__ csr_off, int e) {
    int i = blockIdx.x * blockDim.x + threadIdx.x;
    if (i >= e) return;
    int pos = atomicAdd(&cursor[dst[i]], 1);
    csr_off[pos] = src[i] << 8;  // fp16 row stride = 128*2 = 256 B
}

// ------- MFMA GEMM: Y[n,128](fp16) = (A[n,128] @ W[128,128]) * dinv[row] -------
template <typename T>
__global__ __launch_bounds__(512) void k_gemm_mfma(const T* __restrict__ A,
                                                   const __half* __restrict__ WT,
                                                   const float* __restrict__ dinv,
                                                   __half* __restrict__ C, int n) {
    __shared__ _Float16 as[128 * 128];   // 32 KB  [r][k] swizzled
    __shared__ _Float16 wt[128 * 128];   // 32 KB  [c][k] swizzled
    int t = threadIdx.x;
    int r0 = blockIdx.x * 128;

    for (int i = t; i < 2048; i += 512) {
        int c = i >> 4, k8 = i & 15;
        uint4 u = reinterpret_cast<const uint4*>(WT)[i];
        int byte = (c * 256 + k8 * 16) ^ ((c & 7) << 4);
        *reinterpret_cast<uint4*>(reinterpret_cast<char*>(wt) + byte) = u;
    }

    if constexpr (sizeof(T) == 4) {
        for (int i = t; i < 128 * 16; i += 512) {
            int r = i >> 4, c8 = i & 15;
            float4 v0 = make_float4(0.f, 0.f, 0.f, 0.f);
            float4 v1 = make_float4(0.f, 0.f, 0.f, 0.f);
            if (r0 + r < n) {
                v0 = reinterpret_cast<const float4*>(A)[(size_t)(r0 + r) * 32 + c8 * 2];
                v1 = reinterpret_cast<const float4*>(A)[(size_t)(r0 + r) * 32 + c8 * 2 + 1];
            }
            __half2 h0 = __float22half2_rn(make_float2(v0.x, v0.y));
            __half2 h1 = __float22half2_rn(make_float2(v0.z, v0.w));
            __half2 h2 = __float22half2_rn(make_float2(v1.x, v1.y));
            __half2 h3 = __float22half2_rn(make_float2(v1.z, v1.w));
            uint4 u;
            u.x = *reinterpret_cast<unsigned int*>(&h0);
            u.y = *reinterpret_cast<unsigned int*>(&h1);
            u.z = *reinterpret_cast<unsigned int*>(&h2);
            u.w = *reinterpret_cast<unsigned int*>(&h3);
            int byte = (r * 256 + c8 * 16) ^ ((r & 7) << 4);
            *reinterpret_cast<uint4*>(reinterpret_cast<char*>(as) + byte) = u;
        }
    } else {
        for (int i = t; i < 128 * 16; i += 512) {
            int r = i >> 4, c8 = i & 15;
            uint4 u = make_uint4(0, 0, 0, 0);
            if (r0 + r < n)
                u = reinterpret_cast<const uint4*>(A)[(size_t)(r0 + r) * 16 + c8];
            int byte = (r * 256 + c8 * 16) ^ ((r & 7) << 4);
            *reinterpret_cast<uint4*>(reinterpret_cast<char*>(as) + byte) = u;
        }
    }
    __syncthreads();

    int w = t >> 6, l = t & 63;
    int lrow = l & 15, lk = l >> 4;
    int rw = w * 16;

    f16x8 afrag[4];
    #pragma unroll
    for (int ks = 0; ks < 4; ++ks) {
        int row = rw + lrow;
        int byte = (row * 256 + (ks * 4 + lk) * 16) ^ ((row & 7) << 4);
        afrag[ks] = *reinterpret_cast<const f16x8*>(reinterpret_cast<const char*>(as) + byte);
    }
    float dv[4];
    #pragma unroll
    for (int reg = 0; reg < 4; ++reg) {
        int rg = r0 + rw + lk * 4 + reg;
        dv[reg] = (rg < n) ? dinv[rg] : 0.f;
    }

    #pragma unroll
    for (int ct = 0; ct < 8; ++ct) {
        f32x4 acc = {0.f, 0.f, 0.f, 0.f};
        #pragma unroll
        for (int ks = 0; ks < 4; ++ks) {
            int c = ct * 16 + lrow;
            int byte = (c * 256 + (ks * 4 + lk) * 16) ^ ((c & 7) << 4);
            f16x8 bfrag = *reinterpret_cast<const f16x8*>(reinterpret_cast<const char*>(wt) + byte);
            acc = __builtin_amdgcn_mfma_f32_16x16x32_f16(afrag[ks], bfrag, acc, 0, 0, 0);
        }
        #pragma unroll
        for (int reg = 0; reg < 4; ++reg) {
            int rg = r0 + rw + lk * 4 + reg;
            if (rg < n)
                C[(size_t)rg * FDIM + ct * 16 + lrow] = __float2half(acc[reg] * dv[reg]);
        }
    }
}

// -------- aggregation (both layers): V2 inner loop, 2 edges per dwordx2 load --------
// Lanes 0-31 = even edge, 32-63 = odd edge; offsets via readlane + cndmask (SALU,
// no LDS traffic — R14's shfl variant cost 17.6M bank conflicts). R13-proven 141 us.
template <bool FUSE>
__global__ __launch_bounds__(256) void k_agg2e(const __half* __restrict__ Y,
                                               const int* __restrict__ csr_off,
                                               const int* __restrict__ row_ptr,
                                               const float* __restrict__ dinv,
                                               const float* __restrict__ bias,
                                               const float* __restrict__ Wl,
                                               const float* __restrict__ bl,
                                               __half* __restrict__ hout,
                                               float* __restrict__ out, int n) {
    __shared__ float s_wl[NCLS * FDIM];  // transposed: [c][k]
    __shared__ float s_bl[NCLS];
    if (FUSE) {
        for (int i = threadIdx.x; i < FDIM * NCLS / 4; i += 256) {
            int k = i >> 2, c4 = (i & 3) * 4;
            float4 v = reinterpret_cast<const float4*>(Wl)[i];
            s_wl[(c4 + 0) * FDIM + k] = v.x;
            s_wl[(c4 + 1) * FDIM + k] = v.y;
            s_wl[(c4 + 2) * FDIM + k] = v.z;
            s_wl[(c4 + 3) * FDIM + k] = v.w;
        }
        if (threadIdx.x < NCLS) s_bl[threadIdx.x] = bl[threadIdx.x];
        __syncthreads();
    }

    int node = blockIdx.x * 4 + (threadIdx.x >> 6);
    if (node >= n) return;
    int lane = threadIdx.x & 63;
    int half = lane >> 5, l32 = lane & 31;
    const char* Yb = reinterpret_cast<const char*>(Y);
    const char* lanebase = Yb + (l32 << 3);  // loop-invariant

    float a0 = 0.f, a1 = 0.f, a2 = 0.f, a3 = 0.f;
    int beg = row_ptr[node], end = row_ptr[node + 1];

    for (int j0 = beg; j0 < end; j0 += 64) {
        int cnt = min(64, end - j0);
        int myoff = (j0 + lane < end) ? csr_off[j0 + lane] : 0;
        int k = 0;
        for (; k + 8 <= cnt; k += 8) {
            uint2 u[4];
            #pragma unroll
            for (int i = 0; i < 4; ++i) {
                int oe = __builtin_amdgcn_readlane(myoff, k + 2 * i);
                int oo = __builtin_amdgcn_readlane(myoff, k + 2 * i + 1);
                int off = half ? oo : oe;
                u[i] = *reinterpret_cast<const uint2*>(lanebase + off);
            }
            __half2* p = reinterpret_cast<__half2*>(u);
            __half2 lo = __hadd2(__hadd2(p[0], p[2]), __hadd2(p[4], p[6]));
            __half2 hi = __hadd2(__hadd2(p[1], p[3]), __hadd2(p[5], p[7]));
            float2 flo = __half22float2(lo), fhi = __half22float2(hi);
            a0 += flo.x; a1 += flo.y; a2 += fhi.x; a3 += fhi.y;
        }
        for (; k + 2 <= cnt; k += 2) {
            int oe = __builtin_amdgcn_readlane(myoff, k);
            int oo = __builtin_amdgcn_readlane(myoff, k + 1);
            int off = half ? oo : oe;
            uint2 u = *reinterpret_cast<const uint2*>(lanebase + off);
            __half2* p = reinterpret_cast<__half2*>(&u);
            float2 flo = __half22float2(p[0]), fhi = __half22float2(p[1]);
            a0 += flo.x; a1 += flo.y; a2 += fhi.x; a3 += fhi.y;
        }
        if (k < cnt) {  // odd leftover: only half 0 contributes
            int o = __builtin_amdgcn_readlane(myoff, k);
            uint2 u = *reinterpret_cast<const uint2*>(lanebase + o);
            __half2* p = reinterpret_cast<__half2*>(&u);
            float sel = (half == 0) ? 1.0f : 0.0f;
            float2 flo = __half22float2(p[0]), fhi = __half22float2(p[1]);
            a0 += flo.x * sel; a1 += flo.y * sel;
            a2 += fhi.x * sel; a3 += fhi.y * sel;
        }
    }

    a0 += __shfl_xor(a0, 32, 64);
    a1 += __shfl_xor(a1, 32, 64);
    a2 += __shfl_xor(a2, 32, 64);
    a3 += __shfl_xor(a3, 32, 64);

    // self term (after half-combine: each half's copy gets it exactly once)
    uint2 su = *reinterpret_cast<const uint2*>(Yb + ((size_t)node << 8) + (l32 << 3));
    __half2* sp = reinterpret_cast<__half2*>(&su);
    float2 slo = __half22float2(sp[0]), shi = __half22float2(sp[1]);
    a0 += slo.x; a1 += slo.y; a2 += shi.x; a3 += shi.y;

    float di = dinv[node];
    float4 b = *reinterpret_cast<const float4*>(bias + l32 * 4);
    float h0 = fmaxf(a0 * di + b.x, 0.f);
    float h1 = fmaxf(a1 * di + b.y, 0.f);
    float h2 = fmaxf(a2 * di + b.z, 0.f);
    float h3 = fmaxf(a3 * di + b.w, 0.f);

    if (!FUSE) {
        if (half == 0) {
            __half2 o0 = __float22half2_rn(make_float2(h0, h1));
            __half2 o1 = __float22half2_rn(make_float2(h2, h3));
            uint2 o;
            o.x = *reinterpret_cast<unsigned int*>(&o0);
            o.y = *reinterpret_cast<unsigned int*>(&o1);
            *reinterpret_cast<uint2*>(reinterpret_cast<char*>(hout) + ((size_t)node << 8) + (l32 << 3)) = o;
        }
    } else {
        // per-lane partial logits over this lane's 4 h components (cols 4*l32..+3)
        float lg[NCLS];
        #pragma unroll
        for (int c = 0; c < NCLS; ++c) {
            float4 w4 = *reinterpret_cast<const float4*>(&s_wl[c * FDIM + l32 * 4]);
            lg[c] = h0 * w4.x + h1 * w4.y + h2 * w4.z + h3 * w4.w;
        }
        // butterfly within each 32-lane half (halves identical afterwards)
        #pragma unroll
        for (int off = 1; off < 32; off <<= 1) {
            #pragma unroll
            for (int c = 0; c < NCLS; ++c) lg[c] += __shfl_xor(lg[c], off, 64);
        }
        #pragma unroll
        for (int c = 0; c < NCLS; ++c) lg[c] += s_bl[c];
        float m = lg[0];
        #pragma unroll
        for (int c = 1; c < NCLS; ++c) m = fmaxf(m, lg[c]);
        float ev[NCLS];
        float sum = 0.f;
        #pragma unroll
        for (int c = 0; c < NCLS; ++c) { ev[c] = __expf(lg[c] - m); sum += ev[c]; }
        float inv = 1.0f / sum;
        float mye = 0.f;
        #pragma unroll
        for (int c = 0; c < NCLS; ++c) if (lane == c) mye = ev[c];  // static idx
        if (lane < NCLS) out[(size_t)node * NCLS + lane] = mye * inv;
    }
}

extern "C" void kernel_launch(void* const* d_in, const int* in_sizes, int n_in,
                              void* d_out, int out_size, void* d_ws, size_t ws_size,
                              hipStream_t stream) {
    const float* x  = (const float*)d_in[0];
    const int*   ei = (const int*)d_in[1];
    const float* W1 = (const float*)d_in[2];
    const float* b1 = (const float*)d_in[3];
    const float* W2 = (const float*)d_in[4];
    const float* b2 = (const float*)d_in[5];
    const float* Wl = (const float*)d_in[6];
    const float* bl = (const float*)d_in[7];
    float* out = (float*)d_out;

    int n = in_sizes[0] / FDIM;
    int e = in_sizes[1] / 2;
    const int* src = ei;
    const int* dst = ei + e;

    int nb = (n + SCAN_CHUNK - 1) / SCAN_CHUNK;  // <=1024

    // workspace layout (R11/R13-proven)
    float* dinv    = (float*)d_ws;                     // n
    int*   cnt     = (int*)(dinv + n);                 // n
    int*   row_ptr = cnt + n;                          // n+1
    int*   cursor  = row_ptr + n + 1;                  // n
    int*   blockSum= cursor + n;                       // nb (<=1024)
    int*   total   = blockSum + 1024;                  // 1
    int*   csr_off = total + 1;                        // e
    uintptr_t p = (uintptr_t)(csr_off + e);
    p = (p + 15) & ~(uintptr_t)15;
    __half* wt1 = (__half*)p;                          // 128*128
    __half* wt2 = wt1 + 128 * 128;                     // 128*128
    __half* bufA = wt2 + 128 * 128;                    // n*128 halves
    __half* bufB = bufA + (size_t)n * FDIM;            // n*128 halves

    int bn = (n + 255) / 256;
    int be = (e + 255) / 256;

    // CSR + norms + weight prep
    hipMemsetAsync(cnt, 0, (size_t)n * sizeof(int), stream);
    k_count<<<be, 256, 0, stream>>>(dst, cnt, e);
    k_scan1<<<nb, SCAN_T, 0, stream>>>(cnt, row_ptr, blockSum, dinv, n);
    k_scan2_prepw<<<3, 1024, 0, stream>>>(blockSum, total, nb, W1, W2, wt1, wt2);
    k_scan3<<<bn, 256, 0, stream>>>(row_ptr, cursor, blockSum, total, n);
    k_scatter<<<be, 256, 0, stream>>>(src, dst, cursor, csr_off, e);

    int bg = (n + 127) / 128;
    int ba = (n + 3) / 4;

    // layer 1
    k_gemm_mfma<float><<<bg, 512, 0, stream>>>(x, wt1, dinv, bufA, n);
    k_agg2e<false><<<ba, 256, 0, stream>>>(bufA, csr_off, row_ptr, dinv, b1, Wl, bl, bufB, out, n);

    // layer 2 (+ fused classifier/softmax)
    k_gemm_mfma<__half><<<bg, 512, 0, stream>>>(bufB, wt2, dinv, bufA, n);
    k_agg2e<true><<<ba, 256, 0, stream>>>(bufA, csr_off, row_ptr, dinv, b2, Wl, bl, bufB, out, n);
}